// Round 4
// baseline (7379.853 us; speedup 1.0000x reference)
//
#include <hip/hip_runtime.h>
#include <math.h>

#define NN 250000
#define NE 1250000
#define NC 50000
#define EMBD 200

typedef unsigned int u32;
typedef unsigned short u16;
typedef short s16x8 __attribute__((ext_vector_type(8)));
typedef float f32x4 __attribute__((ext_vector_type(4)));

__device__ __forceinline__ u16 f2bf(float f) {
    u32 u = __float_as_uint(f);
    return (u16)((u + 0x7FFFu + ((u >> 16) & 1u)) >> 16);   // RNE
}
__device__ __forceinline__ u32 cvtpk(float lo, float hi) {  // bf16(lo) | bf16(hi)<<16
    u32 r;
    asm("v_cvt_pk_bf16_f32 %0, %1, %2" : "=v"(r) : "v"(lo), "v"(hi));
    return r;
}
__device__ __forceinline__ float lrelu(float v) { return v > 0.f ? v : 0.01f * v; }
__device__ __forceinline__ u32 encf(float f) {
    u32 u = __float_as_uint(f);
    return (u & 0x80000000u) ? ~u : (u | 0x80000000u);
}
__device__ __forceinline__ float decf(u32 k) {
    return __uint_as_float((k & 0x80000000u) ? (k ^ 0x80000000u) : ~k);
}

// ---------- pack W[K][N] f32 -> fragment-major bf16 (standard B-operand, mfma_16x16x32) ----------
// frag f = ks*(N/16)+ng ; lane (q=lane>>4,c=lane&15) holds W[32*ks+8*q+i][16*ng+c]
__global__ void k_pack(const float* __restrict__ src, u16* __restrict__ dst,
                       int K, int N, int nheads)
{
    const int t = blockIdx.x * 256 + threadIdx.x;
    const int F = (K / 32) * (N / 16);
    if (t >= nheads * F * 64) return;
    const int lane = t & 63;
    const int fh = t >> 6;
    const int f = fh % F, head = fh / F;
    const int ng = f % (N / 16), ks = f / (N / 16);
    const int q = lane >> 4, c = lane & 15;
    const float* s = src + (size_t)head * K * N;
    u16 o[8];
    #pragma unroll
    for (int i = 0; i < 8; ++i)
        o[i] = f2bf(s[(size_t)(32 * ks + 8 * q + i) * N + 16 * ng + c]);
    uint4 v;
    v.x = (u32)o[0] | ((u32)o[1] << 16);
    v.y = (u32)o[2] | ((u32)o[3] << 16);
    v.z = (u32)o[4] | ((u32)o[5] << 16);
    v.w = (u32)o[6] | ((u32)o[7] << 16);
    *(uint4*)(dst + (size_t)head * K * N + ((size_t)f * 64 + lane) * 8) = v;
}

// ---------- pack W2[256][64] with the sH permutation pi ----------
// stored-p -> hidden col: half=p>>7, pl=p&127: col = (pl>>5)*64 + (2*half + (pl&1))*16 + ((pl>>1)&15)
__global__ void k_pack2(const float* __restrict__ src, u16* __restrict__ dst, int nheads)
{
    const int t = blockIdx.x * 256 + threadIdx.x;
    const int F = 32;                       // 8 ks2 * 4 ng
    if (t >= nheads * F * 64) return;
    const int lane = t & 63;
    const int fh = t >> 6;
    const int f = fh % F, head = fh / F;
    const int ks2 = f >> 2, ng = f & 3;
    const int q = lane >> 4, c = lane & 15;
    const int half = ks2 >> 2, k2l = ks2 & 3;
    const float* s = src + (size_t)head * 256 * 64;
    u16 o[8];
    #pragma unroll
    for (int i = 0; i < 8; ++i) {
        const int pl = 32 * k2l + 8 * q + i;            // local stored index in half
        const int krow = (pl >> 5) * 64 + (2 * half + (pl & 1)) * 16 + ((pl >> 1) & 15);
        o[i] = f2bf(s[(size_t)krow * 64 + 16 * ng + c]);
    }
    uint4 v;
    v.x = (u32)o[0] | ((u32)o[1] << 16);
    v.y = (u32)o[2] | ((u32)o[3] << 16);
    v.z = (u32)o[4] | ((u32)o[5] << 16);
    v.w = (u32)o[6] | ((u32)o[7] << 16);
    *(uint4*)(dst + (size_t)head * 256 * 64 + ((size_t)f * 64 + lane) * 8) = v;
}

// ---------- embedding ----------
__global__ __launch_bounds__(256) void k_embed(
    const float* __restrict__ elem_fea, const float* __restrict__ elem_w,
    const float* __restrict__ emb_w, const float* __restrict__ emb_b,
    float* __restrict__ x, u16* __restrict__ xbf)
{
    const int wave = threadIdx.x >> 6, lane = threadIdx.x & 63;
    const int node = blockIdx.x * 4 + wave;
    if (node >= NN) return;
    float acc;
    if (lane < 63) {
        acc = emb_b[lane];
        const float* fr = elem_fea + (size_t)node * EMBD;
        for (int k = 0; k < EMBD; ++k)
            acc += fr[k] * emb_w[k * 63 + lane];
    } else {
        acc = elem_w[node];
    }
    x[(size_t)node * 64 + lane] = acc;
    xbf[(size_t)node * 64 + lane] = f2bf(acc);
}

// ---------- MFMA gate (+ fused segment atomicMax) ----------
template<int KD, bool GATHER>
__global__ __launch_bounds__(256, 4) void k_gate(
    const u16* __restrict__ xbf, const int* __restrict__ sidx, const int* __restrict__ nidx,
    const int* __restrict__ scat, const u16* __restrict__ w1p,
    const float* __restrict__ b1g, const float* __restrict__ w2g,
    float* __restrict__ gate_out, u32* __restrict__ gmax, int nrows, size_t gstride)
{
    constexpr int KS = KD / 32;
    constexpr int RB = KD * 2;
    constexpr int G  = KD / 8;
    __shared__ __align__(16) u16 sA[64 * KD];
    __shared__ float sg[4][64];
    const int tid = threadIdx.x;
    const int r0 = blockIdx.x * 64;
    const int rem = min(64, nrows - r0);

    for (int i = tid; i < 64 * G; i += 256) {
        const int row = i / G, g = i % G;
        const int rr = (row < rem) ? row : 0;
        uint4 v;
        if (GATHER) {
            const int node = (g < G / 2) ? sidx[r0 + rr] : nidx[r0 + rr];
            v = *(const uint4*)(xbf + (size_t)node * 64 + (g & (G / 2 - 1)) * 8);
        } else {
            v = *(const uint4*)(xbf + (size_t)(r0 + rr) * 64 + g * 8);
        }
        *(uint4*)((char*)sA + row * RB + ((g ^ (row & 7)) * 16)) = v;
    }
    __syncthreads();

    const int w = tid >> 6, lane = tid & 63, q = lane >> 4, c = lane & 15;

    for (int h = 0; h < 3; ++h) {
        float part[4][4];
        #pragma unroll
        for (int m = 0; m < 4; ++m)
            #pragma unroll
            for (int r = 0; r < 4; ++r) part[m][r] = 0.f;
        const u16* wp = w1p + (size_t)h * KD * 256;
        #pragma unroll
        for (int half = 0; half < 2; ++half) {
            s16x8 B1[KS][2];
            #pragma unroll
            for (int ks = 0; ks < KS; ++ks)
                #pragma unroll
                for (int n2 = 0; n2 < 2; ++n2)
                    B1[ks][n2] = *(const s16x8*)(wp + ((size_t)(ks * 16 + w * 4 + half * 2 + n2) * 64 + lane) * 8);
            f32x4 acc[4][2];
            #pragma unroll
            for (int m = 0; m < 4; ++m) { acc[m][0] = 0.f; acc[m][1] = 0.f; }
            __builtin_amdgcn_s_setprio(1);
            #pragma unroll
            for (int ks = 0; ks < KS; ++ks) {
                s16x8 a[4];
                #pragma unroll
                for (int m = 0; m < 4; ++m) {
                    const int row = m * 16 + c;
                    a[m] = *(const s16x8*)((const char*)sA + row * RB + (((ks * 4 + q) ^ (row & 7)) * 16));
                }
                #pragma unroll
                for (int n2 = 0; n2 < 2; ++n2)
                    #pragma unroll
                    for (int m = 0; m < 4; ++m)
                        acc[m][n2] = __builtin_amdgcn_mfma_f32_16x16x32_bf16(a[m], B1[ks][n2], acc[m][n2], 0, 0, 0);
            }
            __builtin_amdgcn_s_setprio(0);
            #pragma unroll
            for (int n2 = 0; n2 < 2; ++n2) {
                const int col = w * 64 + (half * 2 + n2) * 16 + c;
                const float b1v = b1g[h * 256 + col];
                const float w2v = w2g[h * 256 + col];
                #pragma unroll
                for (int m = 0; m < 4; ++m)
                    #pragma unroll
                    for (int r = 0; r < 4; ++r)
                        part[m][r] += lrelu(acc[m][n2][r] + b1v) * w2v;
            }
        }
        #pragma unroll
        for (int off = 1; off < 16; off <<= 1)
            #pragma unroll
            for (int m = 0; m < 4; ++m)
                #pragma unroll
                for (int r = 0; r < 4; ++r)
                    part[m][r] += __shfl_xor(part[m][r], off, 64);
        if (c == 0) {
            #pragma unroll
            for (int m = 0; m < 4; ++m)
                #pragma unroll
                for (int r = 0; r < 4; ++r)
                    sg[w][m * 16 + q * 4 + r] = part[m][r];
        }
        __syncthreads();
        if (tid < rem) {
            const float gv = sg[0][tid] + sg[1][tid] + sg[2][tid] + sg[3][tid];
            gate_out[gstride * h + r0 + tid] = gv;
            atomicMax(&gmax[scat[r0 + tid] * 3 + h], encf(gv));
        }
        __syncthreads();
    }
}

// ---------- MFMA msg: halved hidden, packed sH, weighted scatter ----------
template<int KD, bool GATHER>
__global__ __launch_bounds__(256, 4) void k_msg(
    const u16* __restrict__ xbf, const int* __restrict__ sidx, const int* __restrict__ nidx,
    const int* __restrict__ scat, const u16* __restrict__ w1p, const float* __restrict__ b1g,
    const u16* __restrict__ w2p, const float* __restrict__ b2g,
    const float* __restrict__ tbuf, const float* __restrict__ den,
    float* __restrict__ outp, int nrows, size_t gstride)
{
    constexpr int KS = KD / 32;
    constexpr int RB = KD * 2;
    constexpr int G  = KD / 8;
    __shared__ __align__(16) u16 sA[64 * KD];
    __shared__ __align__(16) u16 sH[64 * 128];   // one hidden half, permuted cols, swizzled
    __shared__ float sgf[64][3];
    __shared__ int ssi[64];
    const int tid = threadIdx.x;
    const int r0 = blockIdx.x * 64;
    const int rem = min(64, nrows - r0);

    for (int i = tid; i < 64 * G; i += 256) {
        const int row = i / G, g = i % G;
        const int rr = (row < rem) ? row : 0;
        uint4 v;
        if (GATHER) {
            const int node = (g < G / 2) ? sidx[r0 + rr] : nidx[r0 + rr];
            v = *(const uint4*)(xbf + (size_t)node * 64 + (g & (G / 2 - 1)) * 8);
        } else {
            v = *(const uint4*)(xbf + (size_t)(r0 + rr) * 64 + g * 8);
        }
        *(uint4*)((char*)sA + row * RB + ((g ^ (row & 7)) * 16)) = v;
    }
    if (tid < 64) ssi[tid] = (tid < rem) ? scat[r0 + tid] : 0;
    if (tid < 192) {
        const int row = tid / 3, h = tid % 3;
        if (row < rem) {
            const int s = scat[r0 + row] * 3 + h;
            sgf[row][h] = tbuf[gstride * h + r0 + row] / (den[s] + 1e-10f);
        } else {
            sgf[row][h] = 0.f;
        }
    }
    __syncthreads();

    const int w = tid >> 6, lane = tid & 63, q = lane >> 4, c = lane & 15;
    float wacc[4][4];
    #pragma unroll
    for (int m = 0; m < 4; ++m)
        #pragma unroll
        for (int r = 0; r < 4; ++r) wacc[m][r] = 0.f;

    for (int h = 0; h < 3; ++h) {
        const u16* wp = w1p + (size_t)h * KD * 256;
        #pragma unroll
        for (int half = 0; half < 2; ++half) {
            // GEMM1 half: hidden cols [w*64 + (2*half+{0,1})*16 + c]
            s16x8 B1[KS][2];
            #pragma unroll
            for (int ks = 0; ks < KS; ++ks)
                #pragma unroll
                for (int n2 = 0; n2 < 2; ++n2)
                    B1[ks][n2] = *(const s16x8*)(wp + ((size_t)(ks * 16 + w * 4 + half * 2 + n2) * 64 + lane) * 8);
            f32x4 acc[4][2];
            #pragma unroll
            for (int m = 0; m < 4; ++m) { acc[m][0] = 0.f; acc[m][1] = 0.f; }
            __builtin_amdgcn_s_setprio(1);
            #pragma unroll
            for (int ks = 0; ks < KS; ++ks) {
                s16x8 a[4];
                #pragma unroll
                for (int m = 0; m < 4; ++m) {
                    const int row = m * 16 + c;
                    a[m] = *(const s16x8*)((const char*)sA + row * RB + (((ks * 4 + q) ^ (row & 7)) * 16));
                }
                #pragma unroll
                for (int n2 = 0; n2 < 2; ++n2)
                    #pragma unroll
                    for (int m = 0; m < 4; ++m)
                        acc[m][n2] = __builtin_amdgcn_mfma_f32_16x16x32_bf16(a[m], B1[ks][n2], acc[m][n2], 0, 0, 0);
            }
            __builtin_amdgcn_s_setprio(0);

            __syncthreads();   // previous sH consumers done
            // write hidden half: lane stores u32 {bf16(n2=0), bf16(n2=1)} at p = w*32 + c*2
            const float b1a = b1g[h * 256 + w * 64 + (half * 2 + 0) * 16 + c];
            const float b1b = b1g[h * 256 + w * 64 + (half * 2 + 1) * 16 + c];
            #pragma unroll
            for (int m = 0; m < 4; ++m)
                #pragma unroll
                for (int r = 0; r < 4; ++r) {
                    const int row = m * 16 + q * 4 + r;
                    const u32 pk = cvtpk(lrelu(acc[m][0][r] + b1a), lrelu(acc[m][1][r] + b1b));
                    *(u32*)((char*)sH + row * 256 + (((w * 4 + (c >> 2)) ^ (row & 7)) * 16) + (c & 3) * 4) = pk;
                }
            // B2 frags for this k-half (issued before barrier; drained by it)
            s16x8 B2[4];
            #pragma unroll
            for (int k2 = 0; k2 < 4; ++k2)
                B2[k2] = *(const s16x8*)(w2p + (size_t)h * 256 * 64 + ((size_t)((half * 4 + k2) * 4 + w) * 64 + lane) * 8);
            __syncthreads();

            // GEMM2 partial over this k-half
            f32x4 acc2[4];
            #pragma unroll
            for (int m = 0; m < 4; ++m) acc2[m] = 0.f;
            __builtin_amdgcn_s_setprio(1);
            #pragma unroll
            for (int k2 = 0; k2 < 4; ++k2) {
                #pragma unroll
                for (int m2 = 0; m2 < 4; ++m2) {
                    const int row = m2 * 16 + c;
                    s16x8 a2 = *(const s16x8*)((const char*)sH + row * 256 + (((k2 * 4 + q) ^ (row & 7)) * 16));
                    acc2[m2] = __builtin_amdgcn_mfma_f32_16x16x32_bf16(a2, B2[k2], acc2[m2], 0, 0, 0);
                }
            }
            __builtin_amdgcn_s_setprio(0);
            const float b2v = half ? b2g[h * 64 + w * 16 + c] : 0.f;
            #pragma unroll
            for (int m2 = 0; m2 < 4; ++m2)
                #pragma unroll
                for (int r = 0; r < 4; ++r) {
                    const int row = m2 * 16 + q * 4 + r;
                    wacc[m2][r] += (acc2[m2][r] + b2v) * sgf[row][h];
                }
        }
    }
    #pragma unroll
    for (int m = 0; m < 4; ++m)
        #pragma unroll
        for (int r = 0; r < 4; ++r) {
            const int row = m * 16 + q * 4 + r;
            if (row < rem)
                atomicAdd(&outp[(size_t)ssi[row] * 64 + w * 16 + c], wacc[m][r] * (1.f / 3.f));
        }
}

// ---------- t = w^p * exp(g - gmax); den += t  (planar gate buffer) ----------
__global__ void k_seg_exp(float* __restrict__ gate_t, const int* __restrict__ idx,
                          const int* __restrict__ wi, const float* __restrict__ elem_w,
                          const float* __restrict__ pw, const u32* __restrict__ gmax,
                          float* __restrict__ den, int n, size_t gstride)
{
    int e = blockIdx.x * blockDim.x + threadIdx.x;
    if (e >= n) return;
    int s = idx[e] * 3;
    float wgt = elem_w[wi ? wi[e] : e];
    #pragma unroll
    for (int h = 0; h < 3; ++h) {
        float gm = decf(gmax[s + h]);
        float t = powf(wgt, pw[h]) * expf(gate_t[gstride * h + e] - gm);
        gate_t[gstride * h + e] = t;
        atomicAdd(&den[s + h], t);
    }
}

// ---------- refresh bf16 mirror ----------
__global__ void k_mirror(const float* __restrict__ x, u16* __restrict__ xbf, int n4) {
    int i = blockIdx.x * 256 + threadIdx.x;
    if (i >= n4) return;
    float4 v = *(const float4*)(x + (size_t)i * 4);
    uint2 o;
    o.x = cvtpk(v.x, v.y);
    o.y = cvtpk(v.z, v.w);
    *(uint2*)(xbf + (size_t)i * 4) = o;
}

extern "C" void kernel_launch(void* const* d_in, const int* in_sizes, int n_in,
                              void* d_out, int out_size, void* d_ws, size_t ws_size,
                              hipStream_t stream)
{
    const float* elem_w   = (const float*)d_in[0];
    const float* elem_fea = (const float*)d_in[1];
    const int*   self_idx = (const int*)d_in[2];
    const int*   nbr_idx  = (const int*)d_in[3];
    const int*   cry_idx  = (const int*)d_in[4];
    const float* emb_w    = (const float*)d_in[5];
    const float* emb_b    = (const float*)d_in[6];
    const float* gg_w1    = (const float*)d_in[7];
    const float* gg_b1    = (const float*)d_in[8];
    const float* gg_w2    = (const float*)d_in[9];
    // d_in[10] g_gate_b2 cancels in scatter-softmax
    const float* gm_w1    = (const float*)d_in[11];
    const float* gm_b1    = (const float*)d_in[12];
    const float* gm_w2    = (const float*)d_in[13];
    const float* gm_b2    = (const float*)d_in[14];
    const float* g_pow    = (const float*)d_in[15];
    const float* cg_w1    = (const float*)d_in[16];
    const float* cg_b1    = (const float*)d_in[17];
    const float* cg_w2    = (const float*)d_in[18];
    // d_in[19] c_gate_b2 cancels
    const float* cm_w1    = (const float*)d_in[20];
    const float* cm_b1    = (const float*)d_in[21];
    const float* cm_w2    = (const float*)d_in[22];
    const float* cm_b2    = (const float*)d_in[23];
    const float* c_pow    = (const float*)d_in[24];

    char* wsp = (char*)d_ws;
    size_t off = 0;
    auto alloc = [&](size_t b) { char* p = wsp + off; off += (b + 255) & ~(size_t)255; return p; };
    float* x      = (float*)alloc((size_t)NN * 64 * 4);
    u16*   xbf    = (u16*)  alloc((size_t)NN * 64 * 2);
    float* gate_t = (float*)alloc((size_t)NE * 3 * 4);   // planar [3][stride]
    float* den    = (float*)alloc((size_t)NN * 3 * 4);
    u32*   gmax   = (u32*)  alloc((size_t)NN * 3 * 4);
    float* cden   = (float*)alloc((size_t)NC * 3 * 4);
    u32*   cgmax  = (u32*)  alloc((size_t)NC * 3 * 4);
    u16* wg1p = (u16*)alloc((size_t)9 * 128 * 256 * 2);
    u16* wm1p = (u16*)alloc((size_t)9 * 128 * 256 * 2);
    u16* wm2p = (u16*)alloc((size_t)9 * 256 * 64 * 2);
    u16* cg1p = (u16*)alloc((size_t)3 * 64 * 256 * 2);
    u16* cm1p = (u16*)alloc((size_t)3 * 64 * 256 * 2);
    u16* cm2p = (u16*)alloc((size_t)3 * 256 * 64 * 2);

    auto pack = [&](const float* s, u16* d, int K, int N, int H) {
        int tot = H * (K / 32) * (N / 16) * 64;
        k_pack<<<(tot + 255) / 256, 256, 0, stream>>>(s, d, K, N, H);
    };
    pack(gg_w1, wg1p, 128, 256, 9);
    pack(gm_w1, wm1p, 128, 256, 9);
    pack(cg_w1, cg1p, 64, 256, 3);
    pack(cm_w1, cm1p, 64, 256, 3);
    k_pack2<<<(9 * 32 * 64 + 255) / 256, 256, 0, stream>>>(gm_w2, wm2p, 9);
    k_pack2<<<(3 * 32 * 64 + 255) / 256, 256, 0, stream>>>(cm_w2, cm2p, 3);

    k_embed<<<(NN + 3) / 4, 256, 0, stream>>>(elem_fea, elem_w, emb_w, emb_b, x, xbf);

    const int GE = (NE + 63) / 64;
    for (int l = 0; l < 3; ++l) {
        hipMemsetAsync(gmax, 0, (size_t)NN * 3 * 4, stream);
        hipMemsetAsync(den, 0, (size_t)NN * 3 * 4, stream);
        k_gate<128, true><<<GE, 256, 0, stream>>>(
            xbf, self_idx, nbr_idx, self_idx, wg1p + (size_t)l * 3 * 128 * 256,
            gg_b1 + l * 768, gg_w2 + l * 768, gate_t, gmax, NE, (size_t)NE);
        k_seg_exp<<<(NE + 255) / 256, 256, 0, stream>>>(
            gate_t, self_idx, nbr_idx, elem_w, g_pow + l * 3, gmax, den, NE, (size_t)NE);
        // scatter directly into x (residual); GEMM reads go through stale xbf mirror
        k_msg<128, true><<<GE, 256, 0, stream>>>(
            xbf, self_idx, nbr_idx, self_idx, wm1p + (size_t)l * 3 * 128 * 256,
            gm_b1 + l * 768, wm2p + (size_t)l * 3 * 256 * 64, gm_b2 + l * 192,
            gate_t, den, x, NE, (size_t)NE);
        k_mirror<<<(NN * 64 / 4 + 255) / 256, 256, 0, stream>>>(x, xbf, NN * 64 / 4);
    }

    hipMemsetAsync(cgmax, 0, (size_t)NC * 3 * 4, stream);
    hipMemsetAsync(cden, 0, (size_t)NC * 3 * 4, stream);
    hipMemsetAsync(d_out, 0, (size_t)NC * 64 * 4, stream);
    const int GN = (NN + 63) / 64;
    k_gate<64, false><<<GN, 256, 0, stream>>>(
        xbf, nullptr, nullptr, cry_idx, cg1p, cg_b1, cg_w2, gate_t, cgmax, NN, (size_t)NN);
    k_seg_exp<<<(NN + 255) / 256, 256, 0, stream>>>(
        gate_t, cry_idx, nullptr, elem_w, c_pow, cgmax, cden, NN, (size_t)NN);
    k_msg<64, false><<<GN, 256, 0, stream>>>(
        xbf, nullptr, nullptr, cry_idx, cm1p, cm_b1, cm2p, cm_b2,
        gate_t, cden, (float*)d_out, NN, (size_t)NN);
}

// Round 5
// 5629.335 us; speedup vs baseline: 1.3110x; 1.3110x over previous
//
#include <hip/hip_runtime.h>
#include <math.h>

#define NN 250000
#define NE 1250000
#define NC 50000
#define EMBD 200

typedef unsigned int u32;
typedef unsigned short u16;
typedef short s16x8 __attribute__((ext_vector_type(8)));
typedef float f32x4 __attribute__((ext_vector_type(4)));

__device__ __forceinline__ u16 f2bf(float f) {
    u32 u = __float_as_uint(f);
    return (u16)((u + 0x7FFFu + ((u >> 16) & 1u)) >> 16);   // RNE
}
__device__ __forceinline__ u32 cvtpk(float lo, float hi) {  // bf16(lo) | bf16(hi)<<16
    u32 r;
    asm("v_cvt_pk_bf16_f32 %0, %1, %2" : "=v"(r) : "v"(lo), "v"(hi));
    return r;
}
__device__ __forceinline__ float lrelu(float v) { return v > 0.f ? v : 0.01f * v; }
__device__ __forceinline__ u32 encf(float f) {
    u32 u = __float_as_uint(f);
    return (u & 0x80000000u) ? ~u : (u | 0x80000000u);
}
__device__ __forceinline__ float decf(u32 k) {
    return __uint_as_float((k & 0x80000000u) ? (k ^ 0x80000000u) : ~k);
}

// ---------- pack W[K][N] f32 -> fragment-major bf16 (standard B-operand, mfma_16x16x32) ----------
// frag f = ks*(N/16)+ng ; lane (q=lane>>4,c=lane&15) holds W[32*ks+8*q+i][16*ng+c]
__global__ void k_pack(const float* __restrict__ src, u16* __restrict__ dst,
                       int K, int N, int nheads)
{
    const int t = blockIdx.x * 256 + threadIdx.x;
    const int F = (K / 32) * (N / 16);
    if (t >= nheads * F * 64) return;
    const int lane = t & 63;
    const int fh = t >> 6;
    const int f = fh % F, head = fh / F;
    const int ng = f % (N / 16), ks = f / (N / 16);
    const int q = lane >> 4, c = lane & 15;
    const float* s = src + (size_t)head * K * N;
    u16 o[8];
    #pragma unroll
    for (int i = 0; i < 8; ++i)
        o[i] = f2bf(s[(size_t)(32 * ks + 8 * q + i) * N + 16 * ng + c]);
    uint4 v;
    v.x = (u32)o[0] | ((u32)o[1] << 16);
    v.y = (u32)o[2] | ((u32)o[3] << 16);
    v.z = (u32)o[4] | ((u32)o[5] << 16);
    v.w = (u32)o[6] | ((u32)o[7] << 16);
    *(uint4*)(dst + (size_t)head * K * N + ((size_t)f * 64 + lane) * 8) = v;
}

// ---------- pack W2[256][64] with the sH permutation pi ----------
// stored-p -> hidden col: half=p>>7, pl=p&127: col = (pl>>5)*64 + (2*half + (pl&1))*16 + ((pl>>1)&15)
__global__ void k_pack2(const float* __restrict__ src, u16* __restrict__ dst, int nheads)
{
    const int t = blockIdx.x * 256 + threadIdx.x;
    const int F = 32;                       // 8 ks2 * 4 ng
    if (t >= nheads * F * 64) return;
    const int lane = t & 63;
    const int fh = t >> 6;
    const int f = fh % F, head = fh / F;
    const int ks2 = f >> 2, ng = f & 3;
    const int q = lane >> 4, c = lane & 15;
    const int half = ks2 >> 2, k2l = ks2 & 3;
    const float* s = src + (size_t)head * 256 * 64;
    u16 o[8];
    #pragma unroll
    for (int i = 0; i < 8; ++i) {
        const int pl = 32 * k2l + 8 * q + i;            // local stored index in half
        const int krow = (pl >> 5) * 64 + (2 * half + (pl & 1)) * 16 + ((pl >> 1) & 15);
        o[i] = f2bf(s[(size_t)krow * 64 + 16 * ng + c]);
    }
    uint4 v;
    v.x = (u32)o[0] | ((u32)o[1] << 16);
    v.y = (u32)o[2] | ((u32)o[3] << 16);
    v.z = (u32)o[4] | ((u32)o[5] << 16);
    v.w = (u32)o[6] | ((u32)o[7] << 16);
    *(uint4*)(dst + (size_t)head * 256 * 64 + ((size_t)f * 64 + lane) * 8) = v;
}

// ---------- embedding ----------
__global__ __launch_bounds__(256) void k_embed(
    const float* __restrict__ elem_fea, const float* __restrict__ elem_w,
    const float* __restrict__ emb_w, const float* __restrict__ emb_b,
    float* __restrict__ x, u16* __restrict__ xbf)
{
    const int wave = threadIdx.x >> 6, lane = threadIdx.x & 63;
    const int node = blockIdx.x * 4 + wave;
    if (node >= NN) return;
    float acc;
    if (lane < 63) {
        acc = emb_b[lane];
        const float* fr = elem_fea + (size_t)node * EMBD;
        for (int k = 0; k < EMBD; ++k)
            acc += fr[k] * emb_w[k * 63 + lane];
    } else {
        acc = elem_w[node];
    }
    x[(size_t)node * 64 + lane] = acc;
    xbf[(size_t)node * 64 + lane] = f2bf(acc);
}

// ---------- MFMA gate (+ fused segment atomicMax) ----------
// launch_bounds (256,3): 170-VGPR budget — kernel needs ~160; (256,4)'s 128 cap
// forced a 64/64 vgpr/agpr split and HBM-bound scratch spill (R4 post-mortem).
template<int KD, bool GATHER>
__global__ __launch_bounds__(256, 3) void k_gate(
    const u16* __restrict__ xbf, const int* __restrict__ sidx, const int* __restrict__ nidx,
    const int* __restrict__ scat, const u16* __restrict__ w1p,
    const float* __restrict__ b1g, const float* __restrict__ w2g,
    float* __restrict__ gate_out, u32* __restrict__ gmax, int nrows, size_t gstride)
{
    constexpr int KS = KD / 32;
    constexpr int RB = KD * 2;
    constexpr int G  = KD / 8;
    __shared__ __align__(16) u16 sA[64 * KD];
    __shared__ float sg[4][64];
    const int tid = threadIdx.x;
    const int r0 = blockIdx.x * 64;
    const int rem = min(64, nrows - r0);

    for (int i = tid; i < 64 * G; i += 256) {
        const int row = i / G, g = i % G;
        const int rr = (row < rem) ? row : 0;
        uint4 v;
        if (GATHER) {
            const int node = (g < G / 2) ? sidx[r0 + rr] : nidx[r0 + rr];
            v = *(const uint4*)(xbf + (size_t)node * 64 + (g & (G / 2 - 1)) * 8);
        } else {
            v = *(const uint4*)(xbf + (size_t)(r0 + rr) * 64 + g * 8);
        }
        *(uint4*)((char*)sA + row * RB + ((g ^ (row & 7)) * 16)) = v;
    }
    __syncthreads();

    const int w = tid >> 6, lane = tid & 63, q = lane >> 4, c = lane & 15;

    for (int h = 0; h < 3; ++h) {
        float part[4][4];
        #pragma unroll
        for (int m = 0; m < 4; ++m)
            #pragma unroll
            for (int r = 0; r < 4; ++r) part[m][r] = 0.f;
        const u16* wp = w1p + (size_t)h * KD * 256;
        #pragma unroll
        for (int half = 0; half < 2; ++half) {
            s16x8 B1[KS][2];
            #pragma unroll
            for (int ks = 0; ks < KS; ++ks)
                #pragma unroll
                for (int n2 = 0; n2 < 2; ++n2)
                    B1[ks][n2] = *(const s16x8*)(wp + ((size_t)(ks * 16 + w * 4 + half * 2 + n2) * 64 + lane) * 8);
            f32x4 acc[4][2];
            #pragma unroll
            for (int m = 0; m < 4; ++m) { acc[m][0] = 0.f; acc[m][1] = 0.f; }
            __builtin_amdgcn_s_setprio(1);
            #pragma unroll
            for (int ks = 0; ks < KS; ++ks) {
                s16x8 a[4];
                #pragma unroll
                for (int m = 0; m < 4; ++m) {
                    const int row = m * 16 + c;
                    a[m] = *(const s16x8*)((const char*)sA + row * RB + (((ks * 4 + q) ^ (row & 7)) * 16));
                }
                #pragma unroll
                for (int n2 = 0; n2 < 2; ++n2)
                    #pragma unroll
                    for (int m = 0; m < 4; ++m)
                        acc[m][n2] = __builtin_amdgcn_mfma_f32_16x16x32_bf16(a[m], B1[ks][n2], acc[m][n2], 0, 0, 0);
            }
            __builtin_amdgcn_s_setprio(0);
            #pragma unroll
            for (int n2 = 0; n2 < 2; ++n2) {
                const int col = w * 64 + (half * 2 + n2) * 16 + c;
                const float b1v = b1g[h * 256 + col];
                const float w2v = w2g[h * 256 + col];
                #pragma unroll
                for (int m = 0; m < 4; ++m)
                    #pragma unroll
                    for (int r = 0; r < 4; ++r)
                        part[m][r] += lrelu(acc[m][n2][r] + b1v) * w2v;
            }
        }
        #pragma unroll
        for (int off = 1; off < 16; off <<= 1)
            #pragma unroll
            for (int m = 0; m < 4; ++m)
                #pragma unroll
                for (int r = 0; r < 4; ++r)
                    part[m][r] += __shfl_xor(part[m][r], off, 64);
        if (c == 0) {
            #pragma unroll
            for (int m = 0; m < 4; ++m)
                #pragma unroll
                for (int r = 0; r < 4; ++r)
                    sg[w][m * 16 + q * 4 + r] = part[m][r];
        }
        __syncthreads();
        if (tid < rem) {
            const float gv = sg[0][tid] + sg[1][tid] + sg[2][tid] + sg[3][tid];
            gate_out[gstride * h + r0 + tid] = gv;
            atomicMax(&gmax[scat[r0 + tid] * 3 + h], encf(gv));
        }
        __syncthreads();
    }
}

// ---------- MFMA msg: halved hidden, packed sH, weighted scatter ----------
template<int KD, bool GATHER>
__global__ __launch_bounds__(256, 3) void k_msg(
    const u16* __restrict__ xbf, const int* __restrict__ sidx, const int* __restrict__ nidx,
    const int* __restrict__ scat, const u16* __restrict__ w1p, const float* __restrict__ b1g,
    const u16* __restrict__ w2p, const float* __restrict__ b2g,
    const float* __restrict__ tbuf, const float* __restrict__ den,
    float* __restrict__ outp, int nrows, size_t gstride)
{
    constexpr int KS = KD / 32;
    constexpr int RB = KD * 2;
    constexpr int G  = KD / 8;
    __shared__ __align__(16) u16 sA[64 * KD];
    __shared__ __align__(16) u16 sH[64 * 128];   // one hidden half, permuted cols, swizzled
    __shared__ float sgf[64][3];
    __shared__ int ssi[64];
    const int tid = threadIdx.x;
    const int r0 = blockIdx.x * 64;
    const int rem = min(64, nrows - r0);

    for (int i = tid; i < 64 * G; i += 256) {
        const int row = i / G, g = i % G;
        const int rr = (row < rem) ? row : 0;
        uint4 v;
        if (GATHER) {
            const int node = (g < G / 2) ? sidx[r0 + rr] : nidx[r0 + rr];
            v = *(const uint4*)(xbf + (size_t)node * 64 + (g & (G / 2 - 1)) * 8);
        } else {
            v = *(const uint4*)(xbf + (size_t)(r0 + rr) * 64 + g * 8);
        }
        *(uint4*)((char*)sA + row * RB + ((g ^ (row & 7)) * 16)) = v;
    }
    if (tid < 64) ssi[tid] = (tid < rem) ? scat[r0 + tid] : 0;
    if (tid < 192) {
        const int row = tid / 3, h = tid % 3;
        if (row < rem) {
            const int s = scat[r0 + row] * 3 + h;
            sgf[row][h] = tbuf[gstride * h + r0 + row] / (den[s] + 1e-10f);
        } else {
            sgf[row][h] = 0.f;
        }
    }
    __syncthreads();

    const int w = tid >> 6, lane = tid & 63, q = lane >> 4, c = lane & 15;
    float wacc[4][4];
    #pragma unroll
    for (int m = 0; m < 4; ++m)
        #pragma unroll
        for (int r = 0; r < 4; ++r) wacc[m][r] = 0.f;

    for (int h = 0; h < 3; ++h) {
        const u16* wp = w1p + (size_t)h * KD * 256;
        #pragma unroll
        for (int half = 0; half < 2; ++half) {
            // GEMM1 half: hidden cols [w*64 + (2*half+{0,1})*16 + c]
            s16x8 B1[KS][2];
            #pragma unroll
            for (int ks = 0; ks < KS; ++ks)
                #pragma unroll
                for (int n2 = 0; n2 < 2; ++n2)
                    B1[ks][n2] = *(const s16x8*)(wp + ((size_t)(ks * 16 + w * 4 + half * 2 + n2) * 64 + lane) * 8);
            f32x4 acc[4][2];
            #pragma unroll
            for (int m = 0; m < 4; ++m) { acc[m][0] = 0.f; acc[m][1] = 0.f; }
            __builtin_amdgcn_s_setprio(1);
            #pragma unroll
            for (int ks = 0; ks < KS; ++ks) {
                s16x8 a[4];
                #pragma unroll
                for (int m = 0; m < 4; ++m) {
                    const int row = m * 16 + c;
                    a[m] = *(const s16x8*)((const char*)sA + row * RB + (((ks * 4 + q) ^ (row & 7)) * 16));
                }
                #pragma unroll
                for (int n2 = 0; n2 < 2; ++n2)
                    #pragma unroll
                    for (int m = 0; m < 4; ++m)
                        acc[m][n2] = __builtin_amdgcn_mfma_f32_16x16x32_bf16(a[m], B1[ks][n2], acc[m][n2], 0, 0, 0);
            }
            __builtin_amdgcn_s_setprio(0);

            __syncthreads();   // previous sH consumers done
            // write hidden half: lane stores u32 {bf16(n2=0), bf16(n2=1)} at p = w*32 + c*2
            const float b1a = b1g[h * 256 + w * 64 + (half * 2 + 0) * 16 + c];
            const float b1b = b1g[h * 256 + w * 64 + (half * 2 + 1) * 16 + c];
            #pragma unroll
            for (int m = 0; m < 4; ++m)
                #pragma unroll
                for (int r = 0; r < 4; ++r) {
                    const int row = m * 16 + q * 4 + r;
                    const u32 pk = cvtpk(lrelu(acc[m][0][r] + b1a), lrelu(acc[m][1][r] + b1b));
                    *(u32*)((char*)sH + row * 256 + (((w * 4 + (c >> 2)) ^ (row & 7)) * 16) + (c & 3) * 4) = pk;
                }
            // B2 frags for this k-half (issued before barrier; drained by it)
            s16x8 B2[4];
            #pragma unroll
            for (int k2 = 0; k2 < 4; ++k2)
                B2[k2] = *(const s16x8*)(w2p + (size_t)h * 256 * 64 + ((size_t)((half * 4 + k2) * 4 + w) * 64 + lane) * 8);
            __syncthreads();

            // GEMM2 partial over this k-half
            f32x4 acc2[4];
            #pragma unroll
            for (int m = 0; m < 4; ++m) acc2[m] = 0.f;
            __builtin_amdgcn_s_setprio(1);
            #pragma unroll
            for (int k2 = 0; k2 < 4; ++k2) {
                #pragma unroll
                for (int m2 = 0; m2 < 4; ++m2) {
                    const int row = m2 * 16 + c;
                    s16x8 a2 = *(const s16x8*)((const char*)sH + row * 256 + (((k2 * 4 + q) ^ (row & 7)) * 16));
                    acc2[m2] = __builtin_amdgcn_mfma_f32_16x16x32_bf16(a2, B2[k2], acc2[m2], 0, 0, 0);
                }
            }
            __builtin_amdgcn_s_setprio(0);
            const float b2v = half ? b2g[h * 64 + w * 16 + c] : 0.f;
            #pragma unroll
            for (int m2 = 0; m2 < 4; ++m2)
                #pragma unroll
                for (int r = 0; r < 4; ++r) {
                    const int row = m2 * 16 + q * 4 + r;
                    wacc[m2][r] += (acc2[m2][r] + b2v) * sgf[row][h];
                }
        }
    }
    #pragma unroll
    for (int m = 0; m < 4; ++m)
        #pragma unroll
        for (int r = 0; r < 4; ++r) {
            const int row = m * 16 + q * 4 + r;
            if (row < rem)
                atomicAdd(&outp[(size_t)ssi[row] * 64 + w * 16 + c], wacc[m][r] * (1.f / 3.f));
        }
}

// ---------- t = w^p * exp(g - gmax); den += t  (planar gate buffer) ----------
__global__ void k_seg_exp(float* __restrict__ gate_t, const int* __restrict__ idx,
                          const int* __restrict__ wi, const float* __restrict__ elem_w,
                          const float* __restrict__ pw, const u32* __restrict__ gmax,
                          float* __restrict__ den, int n, size_t gstride)
{
    int e = blockIdx.x * blockDim.x + threadIdx.x;
    if (e >= n) return;
    int s = idx[e] * 3;
    float wgt = elem_w[wi ? wi[e] : e];
    #pragma unroll
    for (int h = 0; h < 3; ++h) {
        float gm = decf(gmax[s + h]);
        float t = powf(wgt, pw[h]) * expf(gate_t[gstride * h + e] - gm);
        gate_t[gstride * h + e] = t;
        atomicAdd(&den[s + h], t);
    }
}

// ---------- refresh bf16 mirror ----------
__global__ void k_mirror(const float* __restrict__ x, u16* __restrict__ xbf, int n4) {
    int i = blockIdx.x * 256 + threadIdx.x;
    if (i >= n4) return;
    float4 v = *(const float4*)(x + (size_t)i * 4);
    uint2 o;
    o.x = cvtpk(v.x, v.y);
    o.y = cvtpk(v.z, v.w);
    *(uint2*)(xbf + (size_t)i * 4) = o;
}

extern "C" void kernel_launch(void* const* d_in, const int* in_sizes, int n_in,
                              void* d_out, int out_size, void* d_ws, size_t ws_size,
                              hipStream_t stream)
{
    const float* elem_w   = (const float*)d_in[0];
    const float* elem_fea = (const float*)d_in[1];
    const int*   self_idx = (const int*)d_in[2];
    const int*   nbr_idx  = (const int*)d_in[3];
    const int*   cry_idx  = (const int*)d_in[4];
    const float* emb_w    = (const float*)d_in[5];
    const float* emb_b    = (const float*)d_in[6];
    const float* gg_w1    = (const float*)d_in[7];
    const float* gg_b1    = (const float*)d_in[8];
    const float* gg_w2    = (const float*)d_in[9];
    // d_in[10] g_gate_b2 cancels in scatter-softmax
    const float* gm_w1    = (const float*)d_in[11];
    const float* gm_b1    = (const float*)d_in[12];
    const float* gm_w2    = (const float*)d_in[13];
    const float* gm_b2    = (const float*)d_in[14];
    const float* g_pow    = (const float*)d_in[15];
    const float* cg_w1    = (const float*)d_in[16];
    const float* cg_b1    = (const float*)d_in[17];
    const float* cg_w2    = (const float*)d_in[18];
    // d_in[19] c_gate_b2 cancels
    const float* cm_w1    = (const float*)d_in[20];
    const float* cm_b1    = (const float*)d_in[21];
    const float* cm_w2    = (const float*)d_in[22];
    const float* cm_b2    = (const float*)d_in[23];
    const float* c_pow    = (const float*)d_in[24];

    char* wsp = (char*)d_ws;
    size_t off = 0;
    auto alloc = [&](size_t b) { char* p = wsp + off; off += (b + 255) & ~(size_t)255; return p; };
    float* x      = (float*)alloc((size_t)NN * 64 * 4);
    u16*   xbf    = (u16*)  alloc((size_t)NN * 64 * 2);
    float* gate_t = (float*)alloc((size_t)NE * 3 * 4);   // planar [3][stride]
    float* den    = (float*)alloc((size_t)NN * 3 * 4);
    u32*   gmax   = (u32*)  alloc((size_t)NN * 3 * 4);
    float* cden   = (float*)alloc((size_t)NC * 3 * 4);
    u32*   cgmax  = (u32*)  alloc((size_t)NC * 3 * 4);
    u16* wg1p = (u16*)alloc((size_t)9 * 128 * 256 * 2);
    u16* wm1p = (u16*)alloc((size_t)9 * 128 * 256 * 2);
    u16* wm2p = (u16*)alloc((size_t)9 * 256 * 64 * 2);
    u16* cg1p = (u16*)alloc((size_t)3 * 64 * 256 * 2);
    u16* cm1p = (u16*)alloc((size_t)3 * 64 * 256 * 2);
    u16* cm2p = (u16*)alloc((size_t)3 * 256 * 64 * 2);

    auto pack = [&](const float* s, u16* d, int K, int N, int H) {
        int tot = H * (K / 32) * (N / 16) * 64;
        k_pack<<<(tot + 255) / 256, 256, 0, stream>>>(s, d, K, N, H);
    };
    pack(gg_w1, wg1p, 128, 256, 9);
    pack(gm_w1, wm1p, 128, 256, 9);
    pack(cg_w1, cg1p, 64, 256, 3);
    pack(cm_w1, cm1p, 64, 256, 3);
    k_pack2<<<(9 * 32 * 64 + 255) / 256, 256, 0, stream>>>(gm_w2, wm2p, 9);
    k_pack2<<<(3 * 32 * 64 + 255) / 256, 256, 0, stream>>>(cm_w2, cm2p, 3);

    k_embed<<<(NN + 3) / 4, 256, 0, stream>>>(elem_fea, elem_w, emb_w, emb_b, x, xbf);

    const int GE = (NE + 63) / 64;
    for (int l = 0; l < 3; ++l) {
        hipMemsetAsync(gmax, 0, (size_t)NN * 3 * 4, stream);
        hipMemsetAsync(den, 0, (size_t)NN * 3 * 4, stream);
        k_gate<128, true><<<GE, 256, 0, stream>>>(
            xbf, self_idx, nbr_idx, self_idx, wg1p + (size_t)l * 3 * 128 * 256,
            gg_b1 + l * 768, gg_w2 + l * 768, gate_t, gmax, NE, (size_t)NE);
        k_seg_exp<<<(NE + 255) / 256, 256, 0, stream>>>(
            gate_t, self_idx, nbr_idx, elem_w, g_pow + l * 3, gmax, den, NE, (size_t)NE);
        // scatter directly into x (residual); GEMM reads go through stale xbf mirror
        k_msg<128, true><<<GE, 256, 0, stream>>>(
            xbf, self_idx, nbr_idx, self_idx, wm1p + (size_t)l * 3 * 128 * 256,
            gm_b1 + l * 768, wm2p + (size_t)l * 3 * 256 * 64, gm_b2 + l * 192,
            gate_t, den, x, NE, (size_t)NE);
        k_mirror<<<(NN * 64 / 4 + 255) / 256, 256, 0, stream>>>(x, xbf, NN * 64 / 4);
    }

    hipMemsetAsync(cgmax, 0, (size_t)NC * 3 * 4, stream);
    hipMemsetAsync(cden, 0, (size_t)NC * 3 * 4, stream);
    hipMemsetAsync(d_out, 0, (size_t)NC * 64 * 4, stream);
    const int GN = (NN + 63) / 64;
    k_gate<64, false><<<GN, 256, 0, stream>>>(
        xbf, nullptr, nullptr, cry_idx, cg1p, cg_b1, cg_w2, gate_t, cgmax, NN, (size_t)NN);
    k_seg_exp<<<(NN + 255) / 256, 256, 0, stream>>>(
        gate_t, cry_idx, nullptr, elem_w, c_pow, cgmax, cden, NN, (size_t)NN);
    k_msg<64, false><<<GN, 256, 0, stream>>>(
        xbf, nullptr, nullptr, cry_idx, cm1p, cm_b1, cm2p, cm_b2,
        gate_t, cden, (float*)d_out, NN, (size_t)NN);
}